// Round 7
// baseline (45.620 us; speedup 1.0000x reference)
//
#include <hip/hip_runtime.h>
#include <hip/hip_bf16.h>

#define NB 16
#define NN 256
#define NH 8
#define ND 64
#define NT 5
#define HD (NH * ND)   // 512

typedef __bf16 bf16x8 __attribute__((ext_vector_type(8)));
typedef __bf16 bf16x4 __attribute__((ext_vector_type(4)));
typedef float  f32x4  __attribute__((ext_vector_type(4)));

__device__ __forceinline__ float4 ld4(const float* __restrict__ p) {
    return *reinterpret_cast<const float4*>(p);
}

__device__ __forceinline__ bf16x8 cvt8(float4 a, float4 b) {
    bf16x8 r;
    r[0] = (__bf16)a.x; r[1] = (__bf16)a.y; r[2] = (__bf16)a.z; r[3] = (__bf16)a.w;
    r[4] = (__bf16)b.x; r[5] = (__bf16)b.y; r[6] = (__bf16)b.z; r[7] = (__bf16)b.w;
    return r;
}

// Transpose a[(h*64+dd)*64*5 + e*5 + t] (fp32) -> wt[h][t][e][dd] (bf16).
__global__ void prep_w_kernel(const float* __restrict__ a, __bf16* __restrict__ wt) {
    int idx = blockIdx.x * 256 + threadIdx.x;
    if (idx >= NH * ND * ND * NT) return;
    int t  = idx % NT;
    int e  = (idx / NT) % ND;
    int dd = (idx / (NT * ND)) % ND;
    int h  = idx / (NT * ND * ND);
    wt[(((h * NT + t) * ND + e) * ND) + dd] = (__bf16)a[idx];
}

template <bool USE_WT>
__global__ __launch_bounds__(256, 4) void mhea_kernel(
    const float* __restrict__ src, const float* __restrict__ dst,
    const float* __restrict__ araw, const __bf16* __restrict__ wt,
    const int* __restrict__ edges, float* __restrict__ out)
{
    // P_t: [t][i(16)][e(64)] bf16, elem-index XOR ((i&7)<<3)      (10 KB)
    __shared__ __bf16 Plds[NT * 16 * 64];
    // Selected/activated output tile: [i(16)][j(256)] f32,
    // float-index XOR ((i&7)<<2)                                   (16 KB)
    __shared__ float Ssel[16 * 256];

    // XCD-chunked swizzle: XCD x (= bid%8, round-robin heuristic) gets a
    // contiguous wg range covering 2 complete b's -> L2-resident working set.
    const int bid = blockIdx.x;
    const int wg  = (bid & 7) * 256 + (bid >> 3);   // bijective, 2048 = 8*256
    const int it  = wg & 15;
    const int h   = (wg >> 4) & 7;
    const int b   = wg >> 7;
    const int i0  = it * 16;

    const int tid = threadIdx.x;
    const int w   = tid >> 6;    // wave 0..3: phase-1 e-tile, phase-2 j-quarter
    const int l   = tid & 63;
    const int il  = l & 15;
    const int kg  = l >> 4;      // lane k-group 0..3

    const float* dbase = dst + (size_t)b * NN * HD + h * ND;
    const int*   erow  = edges + ((size_t)b * NN + i0 + il) * NN;
    const float* sbase = src + (size_t)(b * NN + i0 + il) * HD + h * ND;

    // ---------------- entry: issue all independent loads up front ----------------
    float4 s0 = ld4(sbase + kg * 8);
    float4 s1 = ld4(sbase + kg * 8 + 4);
    float4 s2 = ld4(sbase + 32 + kg * 8);
    float4 s3 = ld4(sbase + 32 + kg * 8 + 4);

    const int jbase = w * 64;
    const float* p0 = dbase + (size_t)(jbase + 0 * 16 + il) * HD + kg * 8;
    const float* p1 = dbase + (size_t)(jbase + 1 * 16 + il) * HD + kg * 8;
    float4 dA0 = ld4(p0), dA1 = ld4(p0 + 4), dA2 = ld4(p0 + 32), dA3 = ld4(p0 + 36);
    float4 dB0 = ld4(p1), dB1 = ld4(p1 + 4), dB2 = ld4(p1 + 32), dB3 = ld4(p1 + 36);
    int4 eA = *reinterpret_cast<const int4*>(erow + jbase + 0 * 16 + kg * 4);
    int4 eB = *reinterpret_cast<const int4*>(erow + jbase + 1 * 16 + kg * 4);

    // ---------------- Phase 1 (swapped operands): this wave's e-tile = w ----------
    // A = W^T rows (e = w*16+il, 8 consecutive dd), B = src (i = il).
    // D: lane holds e = w*16 + kg*4 + r (4 consecutive), i = il  -> 8B LDS write.
    {
        bf16x8 bf0 = cvt8(s0, s1);
        bf16x8 bf1 = cvt8(s2, s3);
        const int e = w * 16 + il;
        #pragma unroll
        for (int t = 0; t < NT; ++t) {
            bf16x8 w0, w1;
            if constexpr (USE_WT) {
                const __bf16* wp = wt + (((h * NT + t) * ND + e) * ND) + kg * 8;
                w0 = *reinterpret_cast<const bf16x8*>(wp);
                w1 = *reinterpret_cast<const bf16x8*>(wp + 32);
            } else {
                #pragma unroll
                for (int jj = 0; jj < 8; ++jj) {
                    w0[jj] = (__bf16)araw[((size_t)(h * ND + kg * 8 + jj) * ND + e) * NT + t];
                    w1[jj] = (__bf16)araw[((size_t)(h * ND + kg * 8 + jj + 32) * ND + e) * NT + t];
                }
            }
            f32x4 pacc = {0.f, 0.f, 0.f, 0.f};
            pacc = __builtin_amdgcn_mfma_f32_16x16x32_bf16(w0, bf0, pacc, 0, 0, 0);
            pacc = __builtin_amdgcn_mfma_f32_16x16x32_bf16(w1, bf1, pacc, 0, 0, 0);
            bf16x4 pk;
            pk[0] = (__bf16)pacc[0];
            pk[1] = (__bf16)pacc[1];
            pk[2] = (__bf16)pacc[2];
            pk[3] = (__bf16)pacc[3];
            const int elem = (w * 16 + kg * 4) ^ ((il & 7) << 3);
            *reinterpret_cast<bf16x4*>(&Plds[t * 1024 + il * 64 + elem]) = pk;
        }
    }

    __syncthreads();

    // B-frags for phase 2: lane (il,kg) reads P[t][il][ks*32+kg*8 .. +7]
    bf16x8 pa[NT][2];
    #pragma unroll
    for (int t = 0; t < NT; ++t) {
        #pragma unroll
        for (int ks = 0; ks < 2; ++ks) {
            const int elem = (ks * 32 + kg * 8) ^ ((il & 7) << 3);
            pa[t][ks] = *reinterpret_cast<const bf16x8*>(&Plds[t * 1024 + il * 64 + elem]);
        }
    }

    // ---------------- Phase 2: 4 j-tiles, NO global stores in the loop ----------
    #define DO_JT(JT, R0, R1, R2, R3, EV)                                             \
    {                                                                                 \
        const bf16x8 cb0 = cvt8(R0, R1);                                              \
        const bf16x8 cb1 = cvt8(R2, R3);                                              \
        const int4 ce = EV;                                                           \
        if ((JT) + 2 < 4) {                                                           \
            const float* np = dbase + (size_t)(jbase + ((JT) + 2) * 16 + il) * HD + kg * 8; \
            R0 = ld4(np); R1 = ld4(np + 4); R2 = ld4(np + 32); R3 = ld4(np + 36);     \
            EV = *reinterpret_cast<const int4*>(erow + jbase + ((JT) + 2) * 16 + kg * 4); \
        }                                                                             \
        f32x4 acc[NT];                                                                \
        _Pragma("unroll")                                                             \
        for (int t = 0; t < NT; ++t) {                                                \
            acc[t] = (f32x4){0.f, 0.f, 0.f, 0.f};                                     \
            acc[t] = __builtin_amdgcn_mfma_f32_16x16x32_bf16(cb0, pa[t][0], acc[t], 0, 0, 0); \
            acc[t] = __builtin_amdgcn_mfma_f32_16x16x32_bf16(cb1, pa[t][1], acc[t], 0, 0, 0); \
        }                                                                             \
        float4 o;                                                                     \
        _Pragma("unroll")                                                             \
        for (int r = 0; r < 4; ++r) {                                                 \
            const int ev = (&ce.x)[r];                                                \
            float x;                                                                  \
            if (ev < 0) { x = -1e10f; }                                               \
            else {                                                                    \
                x = (ev == 0) ? acc[0][r]                                             \
                  : (ev == 1) ? acc[1][r]                                             \
                  : (ev == 2) ? acc[2][r]                                             \
                  : (ev == 3) ? acc[3][r]                                             \
                  :             acc[4][r];                                            \
            }                                                                         \
            (&o.x)[r] = (x >= 0.f) ? x : 0.2f * x;                                    \
        }                                                                             \
        const int jc = (jbase + (JT) * 16 + kg * 4) ^ ((il & 7) << 2);                \
        *reinterpret_cast<float4*>(&Ssel[il * 256 + jc]) = o;                         \
    }

    DO_JT(0, dA0, dA1, dA2, dA3, eA)
    DO_JT(1, dB0, dB1, dB2, dB3, eB)
    DO_JT(2, dA0, dA1, dA2, dA3, eA)
    DO_JT(3, dB0, dB1, dB2, dB3, eB)
    #undef DO_JT

    __syncthreads();

    // ---------------- writeout: full contiguous 1 KB rows ----------------
    // wave w writes rows w*4 .. w*4+3; lane l covers cols l*4..l*4+3.
    float* ob = out + (((size_t)(b * NH + h)) * NN + i0) * NN;
    #pragma unroll
    for (int rr = 0; rr < 4; ++rr) {
        const int ii = w * 4 + rr;
        const float4 v = *reinterpret_cast<const float4*>(
            &Ssel[ii * 256 + ((l * 4) ^ ((ii & 7) << 2))]);
        *reinterpret_cast<float4*>(ob + (size_t)ii * NN + l * 4) = v;
    }
}

extern "C" void kernel_launch(void* const* d_in, const int* in_sizes, int n_in,
                              void* d_out, int out_size, void* d_ws, size_t ws_size,
                              hipStream_t stream) {
    const float* src   = (const float*)d_in[0];
    const float* dst   = (const float*)d_in[1];
    const float* a     = (const float*)d_in[2];
    const int*   edges = (const int*)d_in[3];
    float* out = (float*)d_out;

    const size_t wt_bytes = (size_t)NH * NT * ND * ND * sizeof(__bf16);
    dim3 grid(2048);   // flat; kernel decodes (it,h,b) after XCD swizzle

    if (ws_size >= wt_bytes) {
        __bf16* wt = (__bf16*)d_ws;
        const int total = NH * ND * ND * NT;
        prep_w_kernel<<<(total + 255) / 256, 256, 0, stream>>>(a, wt);
        mhea_kernel<true><<<grid, 256, 0, stream>>>(src, dst, a, wt, edges, out);
    } else {
        mhea_kernel<false><<<grid, 256, 0, stream>>>(src, dst, a, nullptr, edges, out);
    }
}